// Round 1
// baseline (214.636 us; speedup 1.0000x reference)
//
#include <hip/hip_runtime.h>
#include <hip/hip_bf16.h>

#define B_  2
#define S_  2048
#define H_  16
#define D_  64
#define STR 72   // padded LDS row stride (shorts)

typedef __attribute__((ext_vector_type(8))) short bf16x8_t;
typedef __attribute__((ext_vector_type(4))) float f32x4_t;

__device__ __forceinline__ unsigned short f2bf(float f) {
    __hip_bfloat16 h = __float2bfloat16(f);
    return __builtin_bit_cast(unsigned short, h);
}

// ---------------- kernel 1: xpos (rotary * scale) for Q and K, fp32 -> bf16,
// layout (B,S,H*64) -> (B,H,S,64) ----------------
__global__ __launch_bounds__(256) void xpos_kernel(const float* __restrict__ Q,
                                                   const float* __restrict__ K,
                                                   unsigned short* __restrict__ qb,
                                                   unsigned short* __restrict__ kb) {
    int tid = blockIdx.x * 256 + threadIdx.x;   // 2^21 threads
    int i = tid & 31;            // rotary pair index within head (half=32)
    int h = (tid >> 5) & 15;
    int s = (tid >> 9) & 2047;
    int b = tid >> 20;

    float pos = (float)s;
    float bs  = (2.0f * (float)i + 25.6f) / 89.6f;            // (2i + 0.4d)/(1.4d), d=64
    float sc  = exp2f(log2f(bs) * pos * (1.0f / 512.0f));     // bs^(pos/512)
    float invf = exp2f(-(float)i * (13.287712379549449f / 32.0f)); // 10000^(-i/32)
    float ang = pos * invf;
    float sn, cs;
    sincosf(ang, &sn, &cs);

    long inIdx = ((long)(b * S_ + s)) * 1024 + h * 64 + 2 * i;
    float2 xq = *(const float2*)(Q + inIdx);
    float2 xk = *(const float2*)(K + inIdx);

    float cq = cs * sc, sq = sn * sc;          // q: upscale
    float rs = 1.0f / sc;
    float ck = cs * rs, sk = sn * rs;          // k: downscale

    float q0 = xq.x * cq - xq.y * sq;
    float q1 = xq.y * cq + xq.x * sq;
    float k0 = xk.x * ck - xk.y * sk;
    float k1 = xk.y * ck + xk.x * sk;

    long outIdx = ((long)((b * H_ + h) * S_ + s)) * 64 + 2 * i;
    *(unsigned int*)(qb + outIdx) = (unsigned int)f2bf(q0) | ((unsigned int)f2bf(q1) << 16);
    *(unsigned int*)(kb + outIdx) = (unsigned int)f2bf(k0) | ((unsigned int)f2bf(k1) << 16);
}

// ---------------- kernel 2: V transpose + cast: (B,S,H*64) fp32 -> (B,H,64,S) bf16 ---------
__global__ __launch_bounds__(256) void vtr_kernel(const float* __restrict__ V,
                                                  unsigned short* __restrict__ vt) {
    __shared__ float tile[64 * 65];
    int bh = blockIdx.x >> 5;   // 0..31
    int st = blockIdx.x & 31;   // s-tile
    int b = bh >> 4, h = bh & 15;
    int s0 = st * 64;
    int t = threadIdx.x;

#pragma unroll
    for (int it = 0; it < 4; ++it) {
        int f  = it * 256 + t;     // float4 index 0..1023
        int sl = f >> 4;           // local s row
        int d4 = f & 15;           // float4 within row
        float4 v = *(const float4*)(V + ((long)(b * S_ + s0 + sl)) * 1024 + h * 64 + d4 * 4);
        tile[sl * 65 + d4 * 4 + 0] = v.x;
        tile[sl * 65 + d4 * 4 + 1] = v.y;
        tile[sl * 65 + d4 * 4 + 2] = v.z;
        tile[sl * 65 + d4 * 4 + 3] = v.w;
    }
    __syncthreads();

    int d = t >> 2, c = t & 3;   // output row d, s-chunk c (16 elems)
    unsigned int pk[8];
#pragma unroll
    for (int j = 0; j < 8; ++j) {
        float f0 = tile[(c * 16 + 2 * j + 0) * 65 + d];
        float f1 = tile[(c * 16 + 2 * j + 1) * 65 + d];
        pk[j] = (unsigned int)f2bf(f0) | ((unsigned int)f2bf(f1) << 16);
    }
    unsigned short* outp = vt + ((long)(bh * 64 + d)) * S_ + s0 + c * 16;
    ((uint4*)outp)[0] = make_uint4(pk[0], pk[1], pk[2], pk[3]);
    ((uint4*)outp)[1] = make_uint4(pk[4], pk[5], pk[6], pk[7]);
}

// ---------------- kernel 3: flash-style retention main loop ----------------
__global__ __launch_bounds__(256) void retention_kernel(const unsigned short* __restrict__ qb,
                                                        const unsigned short* __restrict__ kb,
                                                        const unsigned short* __restrict__ vt,
                                                        float* __restrict__ out) {
    __shared__ __align__(16) unsigned short Qs[64 * STR];
    __shared__ __align__(16) unsigned short Ks[64 * STR];
    __shared__ __align__(16) unsigned short Vs[64 * STR];      // V^T tile: row=d, col=t
    __shared__ __align__(16) unsigned short Ss[4 * 16 * STR];  // per-wave scores

    int qt = blockIdx.x & 31;   // q tile (interleaved for load balance)
    int bh = blockIdx.x >> 5;
    int q0 = qt * 64;
    int t = threadIdx.x;
    int w = t >> 6, lane = t & 63, quad = lane >> 4, l16 = lane & 15;
    int b = bh >> 4, h = bh & 15;

    // gamma_h = 1 - exp(log(1/32) + h*(log(1/512)-log(1/32))/15)
    float lnv   = -3.4657359027997265f + (float)h * (-2.7725887222397811f / 15.0f);
    float gamma = 1.0f - expf(lnv);
    float l2g   = log2f(gamma);

    // stage Q tile once
    const unsigned short* qg = qb + ((long)bh * S_ + q0) * 64;
#pragma unroll
    for (int it = 0; it < 2; ++it) {
        int idx = it * 256 + t;
        int row = idx >> 3, seg = idx & 7;
        *(uint4*)&Qs[row * STR + seg * 8] = *(const uint4*)(qg + row * 64 + seg * 8);
    }

    // per-lane local decay factors: dl = (row_local) - (col_local), constant over KV loop
    float dloc[4][4], dmask[4][4];
#pragma unroll
    for (int nt = 0; nt < 4; ++nt)
#pragma unroll
        for (int r = 0; r < 4; ++r) {
            int dl = (w * 16 + quad * 4 + r) - (nt * 16 + l16);
            float e = exp2f(l2g * (float)dl);
            dloc[nt][r]  = e;
            dmask[nt][r] = (dl >= 0) ? e : 0.0f;
        }

    f32x4_t acc[4];
#pragma unroll
    for (int nt = 0; nt < 4; ++nt) acc[nt] = (f32x4_t){0.f, 0.f, 0.f, 0.f};

    const unsigned short* kgBase = kb + (long)bh * S_ * 64;
    const unsigned short* vgBase = vt + (long)bh * 64 * S_;

    for (int kt = 0; kt <= qt; ++kt) {
        __syncthreads();   // previous iteration's LDS reads done before overwrite
        const unsigned short* kg = kgBase + kt * 64 * 64;
#pragma unroll
        for (int it = 0; it < 2; ++it) {
            int idx = it * 256 + t;
            int row = idx >> 3, seg = idx & 7;
            *(uint4*)&Ks[row * STR + seg * 8] = *(const uint4*)(kg + row * 64 + seg * 8);
            *(uint4*)&Vs[row * STR + seg * 8] =
                *(const uint4*)(vgBase + (long)row * S_ + kt * 64 + seg * 8);
        }
        __syncthreads();

        // ---- S = Q K^T (16x64 per wave) ----
        f32x4_t sc4[4];
#pragma unroll
        for (int nt = 0; nt < 4; ++nt) sc4[nt] = (f32x4_t){0.f, 0.f, 0.f, 0.f};
#pragma unroll
        for (int kk = 0; kk < 2; ++kk) {
            bf16x8_t afr = *(const bf16x8_t*)&Qs[(w * 16 + l16) * STR + kk * 32 + quad * 8];
#pragma unroll
            for (int nt = 0; nt < 4; ++nt) {
                bf16x8_t bfr = *(const bf16x8_t*)&Ks[(nt * 16 + l16) * STR + kk * 32 + quad * 8];
                sc4[nt] = __builtin_amdgcn_mfma_f32_16x16x32_bf16(afr, bfr, sc4[nt], 0, 0, 0);
            }
        }

        // ---- decay multiply + C-layout -> A-layout via LDS ----
        unsigned short* ssw = &Ss[w * 16 * STR];
        if (kt == qt) {   // diagonal tile: mask needed, tile factor = 1
#pragma unroll
            for (int nt = 0; nt < 4; ++nt)
#pragma unroll
                for (int r = 0; r < 4; ++r) {
                    float v = sc4[nt][r] * dmask[nt][r];
                    ssw[(quad * 4 + r) * STR + nt * 16 + l16] = f2bf(v);
                }
        } else {          // strictly-lower tile: always unmasked (delta >= 1)
            float gt = exp2f(l2g * (float)((qt - kt) * 64));
#pragma unroll
            for (int nt = 0; nt < 4; ++nt)
#pragma unroll
                for (int r = 0; r < 4; ++r) {
                    float v = sc4[nt][r] * (gt * dloc[nt][r]);
                    ssw[(quad * 4 + r) * STR + nt * 16 + l16] = f2bf(v);
                }
        }

        // ---- O += S V  (B-fragments from V^T tile: contiguous reads) ----
#pragma unroll
        for (int kk = 0; kk < 2; ++kk) {
            bf16x8_t afr = *(const bf16x8_t*)&ssw[l16 * STR + kk * 32 + quad * 8];
#pragma unroll
            for (int nt = 0; nt < 4; ++nt) {
                bf16x8_t bfr = *(const bf16x8_t*)&Vs[(nt * 16 + l16) * STR + kk * 32 + quad * 8];
                acc[nt] = __builtin_amdgcn_mfma_f32_16x16x32_bf16(afr, bfr, acc[nt], 0, 0, 0);
            }
        }
    }

    // ---- epilogue: C layout row=quad*4+r, col=l16 ----
#pragma unroll
    for (int nt = 0; nt < 4; ++nt)
#pragma unroll
        for (int r = 0; r < 4; ++r) {
            int srow = q0 + w * 16 + quad * 4 + r;
            out[((long)(b * S_ + srow)) * 1024 + h * 64 + nt * 16 + l16] = acc[nt][r];
        }
}

extern "C" void kernel_launch(void* const* d_in, const int* in_sizes, int n_in,
                              void* d_out, int out_size, void* d_ws, size_t ws_size,
                              hipStream_t stream) {
    const float* Q = (const float*)d_in[0];
    const float* K = (const float*)d_in[1];
    const float* V = (const float*)d_in[2];
    float* out = (float*)d_out;

    const size_t perBuf = (size_t)B_ * H_ * S_ * D_;   // 4,194,304 elems (bf16)
    unsigned short* qb = (unsigned short*)d_ws;
    unsigned short* kb = qb + perBuf;
    unsigned short* vt = kb + perBuf;

    hipLaunchKernelGGL(xpos_kernel, dim3(8192), dim3(256), 0, stream, Q, K, qb, kb);
    hipLaunchKernelGGL(vtr_kernel,  dim3(1024), dim3(256), 0, stream, V, vt);
    hipLaunchKernelGGL(retention_kernel, dim3(1024), dim3(256), 0, stream, qb, kb, vt, out);
}

// Round 2
// 165.777 us; speedup vs baseline: 1.2947x; 1.2947x over previous
//
#include <hip/hip_runtime.h>
#include <hip/hip_bf16.h>
#include <math.h>

#define B_  2
#define S_  2048
#define H_  16
#define D_  64
#define STR 72   // padded LDS row stride (shorts): rows land on disjoint bank quads

typedef __attribute__((ext_vector_type(8))) short bf16x8_t;
typedef __attribute__((ext_vector_type(4))) float f32x4_t;

__device__ __forceinline__ unsigned short f2bf(float f) {
    __hip_bfloat16 h = __float2bfloat16(f);
    return __builtin_bit_cast(unsigned short, h);
}

// ---------------- kernel 1: xpos (rotary * xpos-scale * DECAY) for Q and K ----------------
// q <- q * gamma_h^s (rotated, upscaled); k <- k * gamma_h^(-s) (rotated, downscaled)
// This folds the decay mask gamma^(n-m) into the QK^T matmul; retention needs only
// the causal zero-mask on the diagonal tile. Layout (B,S,H*64) fp32 -> (B,H,S,64) bf16.
__global__ __launch_bounds__(256) void xpos_kernel(const float* __restrict__ Q,
                                                   const float* __restrict__ K,
                                                   unsigned short* __restrict__ qb,
                                                   unsigned short* __restrict__ kb) {
    int tid = blockIdx.x * 256 + threadIdx.x;   // 131072 threads total
    int i = tid & 31;            // rotary pair index (half = 32)
    int s = (tid >> 5) & 2047;
    int b = tid >> 16;

    float pos = (float)s;
    float bs  = (2.0f * (float)i + 25.6f) / 89.6f;             // (2i + 0.4d)/(1.4d), d=64
    float sc  = exp2f(log2f(bs) * pos * (1.0f / 512.0f));      // bs^(pos/512)
    float invf = exp2f(-(float)i * (13.287712379549449f / 32.0f)); // 10000^(-i/32)
    float sn, cs;
    sincosf(pos * invf, &sn, &cs);
    float rsc = 1.0f / sc;

    const float* qrow = Q + ((long)(b * S_ + s)) * 1024;
    const float* krow = K + ((long)(b * S_ + s)) * 1024;
    unsigned short* qo = qb + ((long)(b * H_) * S_ + s) * 64 + 2 * i;
    unsigned short* ko = kb + ((long)(b * H_) * S_ + s) * 64 + 2 * i;

#pragma unroll
    for (int h = 0; h < 16; ++h) {
        float lnv   = -3.4657359027997265f + (float)h * (-0.18483924814931874f);
        float gamma = 1.0f - expf(lnv);
        float l2g   = log2f(gamma);
        float gs    = exp2f(pos * l2g);     // gamma^s   (<= 1)
        float gsi   = exp2f(-pos * l2g);    // gamma^-s  (up to ~1.7e28, fine in bf16)

        float cq = cs * sc * gs,   sq = sn * sc * gs;
        float ck = cs * rsc * gsi, sk = sn * rsc * gsi;

        float2 xq = *(const float2*)(qrow + h * 64 + 2 * i);
        float2 xk = *(const float2*)(krow + h * 64 + 2 * i);
        float q0 = xq.x * cq - xq.y * sq, q1 = xq.y * cq + xq.x * sq;
        float k0 = xk.x * ck - xk.y * sk, k1 = xk.y * ck + xk.x * sk;

        *(unsigned int*)(qo + (long)h * S_ * 64) =
            (unsigned)f2bf(q0) | ((unsigned)f2bf(q1) << 16);
        *(unsigned int*)(ko + (long)h * S_ * 64) =
            (unsigned)f2bf(k0) | ((unsigned)f2bf(k1) << 16);
    }
}

// ---------------- kernel 2: V transpose + cast: (B,S,H*64) fp32 -> (B,H,64,S) bf16 -------
__global__ __launch_bounds__(256) void vtr_kernel(const float* __restrict__ V,
                                                  unsigned short* __restrict__ vt) {
    __shared__ float tile[64 * 65];
    int bh = blockIdx.x >> 5;
    int st = blockIdx.x & 31;
    int b = bh >> 4, h = bh & 15;
    int s0 = st * 64;
    int t = threadIdx.x;

#pragma unroll
    for (int it = 0; it < 4; ++it) {
        int f  = it * 256 + t;
        int sl = f >> 4;
        int d4 = f & 15;
        float4 v = *(const float4*)(V + ((long)(b * S_ + s0 + sl)) * 1024 + h * 64 + d4 * 4);
        tile[sl * 65 + d4 * 4 + 0] = v.x;
        tile[sl * 65 + d4 * 4 + 1] = v.y;
        tile[sl * 65 + d4 * 4 + 2] = v.z;
        tile[sl * 65 + d4 * 4 + 3] = v.w;
    }
    __syncthreads();

    int d = t >> 2, c = t & 3;
    unsigned int pk[8];
#pragma unroll
    for (int j = 0; j < 8; ++j) {
        float f0 = tile[(c * 16 + 2 * j + 0) * 65 + d];
        float f1 = tile[(c * 16 + 2 * j + 1) * 65 + d];
        pk[j] = (unsigned int)f2bf(f0) | ((unsigned int)f2bf(f1) << 16);
    }
    unsigned short* outp = vt + ((long)(bh * 64 + d)) * S_ + s0 + c * 16;
    ((uint4*)outp)[0] = make_uint4(pk[0], pk[1], pk[2], pk[3]);
    ((uint4*)outp)[1] = make_uint4(pk[4], pk[5], pk[6], pk[7]);
}

// ---------------- kernel 3: barrier-free, wave-independent retention ----------------
// One wave owns 32 q-rows (2 MFMA m-tiles). Q A-frags live in registers for the whole
// kernel. K/V B-frags come straight from global (L1). Per-wave private LDS only for the
// score C-layout -> A-layout transform. NO __syncthreads anywhere.
__global__ __launch_bounds__(256, 2) void retention_kernel(const unsigned short* __restrict__ qb,
                                                           const unsigned short* __restrict__ kb,
                                                           const unsigned short* __restrict__ vt,
                                                           float* __restrict__ out) {
    __shared__ __align__(16) unsigned short Ss[4][32 * STR];   // 4.5 KB per wave

    int t = threadIdx.x;
    int w = t >> 6, lane = t & 63, quad = lane >> 4, l16 = lane & 15;

    // anti-correlated length map: CU-neighbors get complementary-length jobs
    int j  = blockIdx.x >> 3;                       // 0..63
    int qg = (j < 32) ? (2 * j) : (127 - 2 * j);    // bijection onto 0..63
    int bh = ((blockIdx.x & 7) << 2) + w;           // wave-private head
    int b = bh >> 4, hh = bh & 15;
    int q0 = qg * 32;
    int ktmax = qg >> 1;                            // diagonal kv-tile index
    int odd = qg & 1;

    const unsigned short* qB = qb + ((long)bh * S_ + q0) * 64;
    const unsigned short* kB = kb + (long)bh * S_ * 64;
    const unsigned short* vB = vt + (long)bh * 64 * S_;
    unsigned short* ss = Ss[w];

    // Q A-fragments, held in VGPRs for the whole kernel (A: row=l16, k=quad*8+j)
    bf16x8_t aQ[2][2];
#pragma unroll
    for (int m = 0; m < 2; ++m)
#pragma unroll
        for (int kk = 0; kk < 2; ++kk)
            aQ[m][kk] = *(const bf16x8_t*)(qB + (m * 16 + l16) * 64 + kk * 32 + quad * 8);

    f32x4_t acc[2][4];
#pragma unroll
    for (int m = 0; m < 2; ++m)
#pragma unroll
        for (int nd = 0; nd < 4; ++nd) acc[m][nd] = (f32x4_t){0.f, 0.f, 0.f, 0.f};

    // ---- full KV tiles (no masking: decay already folded into Q/K) ----
    for (int kt = 0; kt < ktmax; ++kt) {
        const unsigned short* kp = kB + kt * 64 * 64;
        bf16x8_t bK[4][2];
#pragma unroll
        for (int nt = 0; nt < 4; ++nt)
#pragma unroll
            for (int kk = 0; kk < 2; ++kk)
                bK[nt][kk] = *(const bf16x8_t*)(kp + (nt * 16 + l16) * 64 + kk * 32 + quad * 8);

        f32x4_t sc[2][4];
#pragma unroll
        for (int m = 0; m < 2; ++m)
#pragma unroll
            for (int nt = 0; nt < 4; ++nt) sc[m][nt] = (f32x4_t){0.f, 0.f, 0.f, 0.f};
#pragma unroll
        for (int kk = 0; kk < 2; ++kk)
#pragma unroll
            for (int m = 0; m < 2; ++m)
#pragma unroll
                for (int nt = 0; nt < 4; ++nt)
                    sc[m][nt] = __builtin_amdgcn_mfma_f32_16x16x32_bf16(aQ[m][kk], bK[nt][kk],
                                                                        sc[m][nt], 0, 0, 0);

        // V B-frags (independent of the score path; loads overlap the LDS round-trip)
        bf16x8_t bV[4][2];
#pragma unroll
        for (int nd = 0; nd < 4; ++nd)
#pragma unroll
            for (int kp2 = 0; kp2 < 2; ++kp2)
                bV[nd][kp2] = *(const bf16x8_t*)(vB + (long)(nd * 16 + l16) * S_ + kt * 64 +
                                                 kp2 * 32 + quad * 8);

        // C layout (row=quad*4+r, col=l16) -> bf16 -> per-wave LDS
#pragma unroll
        for (int m = 0; m < 2; ++m)
#pragma unroll
            for (int nt = 0; nt < 4; ++nt)
#pragma unroll
                for (int r = 0; r < 4; ++r)
                    ss[(m * 16 + quad * 4 + r) * STR + nt * 16 + l16] = f2bf(sc[m][nt][r]);

        bf16x8_t aS[2][2];
#pragma unroll
        for (int m = 0; m < 2; ++m)
#pragma unroll
            for (int kp2 = 0; kp2 < 2; ++kp2)
                aS[m][kp2] = *(const bf16x8_t*)&ss[(m * 16 + l16) * STR + kp2 * 32 + quad * 8];

#pragma unroll
        for (int kp2 = 0; kp2 < 2; ++kp2)
#pragma unroll
            for (int m = 0; m < 2; ++m)
#pragma unroll
                for (int nd = 0; nd < 4; ++nd)
                    acc[m][nd] = __builtin_amdgcn_mfma_f32_16x16x32_bf16(aS[m][kp2], bV[nd][kp2],
                                                                         acc[m][nd], 0, 0, 0);
    }

    // ---- diagonal tile: causal mask, valid cols = odd ? 64 : 32 ----
    {
        const unsigned short* kp = kB + ktmax * 64 * 64;
        int ntv = odd ? 4 : 2;      // valid 16-col score tiles
        int kpv = odd ? 2 : 1;      // valid 32-col PV k-steps

        bf16x8_t bK[4][2];
#pragma unroll
        for (int nt = 0; nt < 4; ++nt)
            if (nt < ntv)
#pragma unroll
                for (int kk = 0; kk < 2; ++kk)
                    bK[nt][kk] =
                        *(const bf16x8_t*)(kp + (nt * 16 + l16) * 64 + kk * 32 + quad * 8);

        f32x4_t sc[2][4];
#pragma unroll
        for (int m = 0; m < 2; ++m)
#pragma unroll
            for (int nt = 0; nt < 4; ++nt) sc[m][nt] = (f32x4_t){0.f, 0.f, 0.f, 0.f};
#pragma unroll
        for (int kk = 0; kk < 2; ++kk)
#pragma unroll
            for (int m = 0; m < 2; ++m)
#pragma unroll
                for (int nt = 0; nt < 4; ++nt)
                    if (nt < ntv)
                        sc[m][nt] = __builtin_amdgcn_mfma_f32_16x16x32_bf16(
                            aQ[m][kk], bK[nt][kk], sc[m][nt], 0, 0, 0);

        bf16x8_t bV[4][2];
#pragma unroll
        for (int nd = 0; nd < 4; ++nd)
#pragma unroll
            for (int kp2 = 0; kp2 < 2; ++kp2)
                if (kp2 < kpv)
                    bV[nd][kp2] = *(const bf16x8_t*)(vB + (long)(nd * 16 + l16) * S_ +
                                                     ktmax * 64 + kp2 * 32 + quad * 8);

        // mask: keep element iff (global row) >= (global col)
        // rows: q0 + m*16 + quad*4 + r ; cols: ktmax*64 + nt*16 + l16 ; q0 - ktmax*64 = odd*32
#pragma unroll
        for (int m = 0; m < 2; ++m)
#pragma unroll
            for (int nt = 0; nt < 4; ++nt) {
                if (nt >= ntv) continue;
                int dlt = (odd * 2 + m - nt) * 16;
#pragma unroll
                for (int r = 0; r < 4; ++r) {
                    int rr = quad * 4 + r;
                    float v = ((rr + dlt) >= l16) ? sc[m][nt][r] : 0.0f;
                    ss[(m * 16 + rr) * STR + nt * 16 + l16] = f2bf(v);
                }
            }

        bf16x8_t aS[2][2];
#pragma unroll
        for (int m = 0; m < 2; ++m)
#pragma unroll
            for (int kp2 = 0; kp2 < 2; ++kp2)
                if (kp2 < kpv)
                    aS[m][kp2] =
                        *(const bf16x8_t*)&ss[(m * 16 + l16) * STR + kp2 * 32 + quad * 8];

#pragma unroll
        for (int kp2 = 0; kp2 < 2; ++kp2)
#pragma unroll
            for (int m = 0; m < 2; ++m)
#pragma unroll
                for (int nd = 0; nd < 4; ++nd)
                    if (kp2 < kpv)
                        acc[m][nd] = __builtin_amdgcn_mfma_f32_16x16x32_bf16(
                            aS[m][kp2], bV[nd][kp2], acc[m][nd], 0, 0, 0);
    }

    // ---- epilogue: C layout row=quad*4+r, col=l16 ----
#pragma unroll
    for (int m = 0; m < 2; ++m)
#pragma unroll
        for (int nd = 0; nd < 4; ++nd)
#pragma unroll
            for (int r = 0; r < 4; ++r) {
                int row = q0 + m * 16 + quad * 4 + r;
                out[((long)(b * S_ + row)) * 1024 + hh * 64 + nd * 16 + l16] = acc[m][nd][r];
            }
}

extern "C" void kernel_launch(void* const* d_in, const int* in_sizes, int n_in,
                              void* d_out, int out_size, void* d_ws, size_t ws_size,
                              hipStream_t stream) {
    const float* Q = (const float*)d_in[0];
    const float* K = (const float*)d_in[1];
    const float* V = (const float*)d_in[2];
    float* out = (float*)d_out;

    const size_t perBuf = (size_t)B_ * H_ * S_ * D_;   // 4,194,304 bf16 elems
    unsigned short* qb = (unsigned short*)d_ws;
    unsigned short* kb = qb + perBuf;
    unsigned short* vt = kb + perBuf;

    hipLaunchKernelGGL(xpos_kernel, dim3(512), dim3(256), 0, stream, Q, K, qb, kb);
    hipLaunchKernelGGL(vtr_kernel,  dim3(1024), dim3(256), 0, stream, V, vt);
    hipLaunchKernelGGL(retention_kernel, dim3(512), dim3(256), 0, stream, qb, kb, vt, out);
}